// Round 1
// baseline (698.728 us; speedup 1.0000x reference)
//
#include <hip/hip_runtime.h>
#include <hip/hip_bf16.h>

// SpecAttn: out = softmax((x@Wq+bq)(x@Wk+bk)^T / 32) @ (x@Wv+bv) @ Wo + bo
// B=8, S=2048, H=1024. bf16 MFMA everywhere, fp32 accumulate.
// R6: counted-vmcnt ring pipeline (T3/T4). 3-slot LDS ring (A0..A2/B0..B2,
//     48KB), prefetch depth 2: iteration t stages tile t+2, then waits
//     s_waitcnt vmcnt(8) -> only tile t's loads are forced complete; tiles
//     t+1/t+2 stay IN FLIGHT across the raw s_barrier (never drained to 0
//     until the 2-iteration epilogue vmcnt(4)/vmcnt(0)). Each tile gets two
//     full compute iterations of latency cover instead of one phase.
//     Raw __builtin_amdgcn_s_barrier (no compiler vmcnt(0) drain) +
//     sched_barrier(0)/"memory" fences pin ordering. setprio(1) around the
//     MFMA cluster. Slots are macro-unrolled (x3 chunks) so all LDS
//     addresses are compile-time and the LDS scoreboard stays counted.
//     128x128 tile, 4 waves, launch_bounds(256,3) -> 3 blocks/CU.

typedef __attribute__((ext_vector_type(8))) __bf16 bf16x8;
typedef __attribute__((ext_vector_type(4))) __bf16 bf16x4;
typedef __attribute__((ext_vector_type(4))) float  f32x4;
typedef __attribute__((ext_vector_type(8))) float  f32x8;

__device__ __forceinline__ void gl_lds16(const void* g, void* l) {
    __builtin_amdgcn_global_load_lds(
        (__attribute__((address_space(1))) const void*)g,
        (__attribute__((address_space(3))) void*)l, 16, 0, 0);
}

// ---------------- fp32 -> bf16 convert (x) ----------------
__global__ __launch_bounds__(256) void k_convert(const float* __restrict__ in,
                                                 __bf16* __restrict__ out) {
    const int i = blockIdx.x * 256 + threadIdx.x;   // 8 elems/thread, exact fit
    f32x8 a = *((const f32x8*)in + i);
    bf16x8 o;
#pragma unroll
    for (int j = 0; j < 8; ++j) o[j] = (__bf16)a[j];
    *((bf16x8*)out + i) = o;
}

// --- fp32 W[k][n] -> bf16 Wt[n][k] (1024x1024), z selects weight ---
__global__ __launch_bounds__(256) void k_transpose_w(
    const float* __restrict__ w0, const float* __restrict__ w1,
    const float* __restrict__ w2, const float* __restrict__ w3,
    __bf16* __restrict__ Wt) {
    const int z = blockIdx.z;
    const float* W = (z == 0) ? w0 : (z == 1) ? w1 : (z == 2) ? w2 : w3;
    __bf16* Wo = Wt + (long long)z * 1048576;
    __shared__ float t[64][65];
    const int tid = threadIdx.x;
    const int c4 = (tid & 15) * 4, r0 = tid >> 4;
    const int bx = blockIdx.x * 64, by = blockIdx.y * 64;
#pragma unroll
    for (int p = 0; p < 4; ++p) {
        const int r = r0 + p * 16;
        f32x4 v = *(const f32x4*)(W + (long long)(by + r) * 1024 + bx + c4);
#pragma unroll
        for (int j = 0; j < 4; ++j) t[r][c4 + j] = v[j];
    }
    __syncthreads();
#pragma unroll
    for (int p = 0; p < 4; ++p) {
        const int r = r0 + p * 16;
        bf16x4 o;
#pragma unroll
        for (int j = 0; j < 4; ++j) o[j] = (__bf16)t[c4 + j][r];
        *(bf16x4*)(Wo + (long long)(bx + r) * 1024 + by + c4) = o;
    }
}

// ------------- concat biases into bcat[3072] fp32 -------------
__global__ __launch_bounds__(256) void k_bcat(const float* __restrict__ bq,
                                              const float* __restrict__ bk,
                                              const float* __restrict__ bv,
                                              float* __restrict__ bc) {
    const int i = blockIdx.x * 256 + threadIdx.x;  // grid 12 -> 3072
    const float* s = (i < 1024) ? bq : (i < 2048 ? bk : bv);
    bc[i] = s[i & 1023];
}

// ------------- row softmax over 2048 cols, in place, bf16 -------------
__global__ __launch_bounds__(256) void k_softmax(__bf16* __restrict__ E) {
    __bf16* p = E + (long long)blockIdx.x * 2048;
    const int tid = threadIdx.x, l = tid & 63, w = tid >> 6;
    bf16x8 vb = *((const bf16x8*)p + tid);
    float v[8];
#pragma unroll
    for (int i = 0; i < 8; ++i) v[i] = (float)vb[i];
    float m = v[0];
#pragma unroll
    for (int i = 1; i < 8; ++i) m = fmaxf(m, v[i]);
    for (int off = 32; off > 0; off >>= 1) m = fmaxf(m, __shfl_xor(m, off));
    __shared__ float redm[4], reds[4];
    if (l == 0) redm[w] = m;
    __syncthreads();
    m = fmaxf(fmaxf(redm[0], redm[1]), fmaxf(redm[2], redm[3]));
    float e[8], s = 0.f;
#pragma unroll
    for (int i = 0; i < 8; ++i) { e[i] = __expf(v[i] - m); s += e[i]; }
    for (int off = 32; off > 0; off >>= 1) s += __shfl_xor(s, off);
    if (l == 0) reds[w] = s;
    __syncthreads();
    s = reds[0] + reds[1] + reds[2] + reds[3];
    const float inv = 1.0f / s;
    bf16x8 o;
#pragma unroll
    for (int i = 0; i < 8; ++i) o[i] = (__bf16)(e[i] * inv);
    *((bf16x8*)p + tid) = o;
}

// ------------- GEMM: C[z] = A[z] @ Bt[z]^T * scale (+bias) -------------
// 128x128 tile, BK=32, 4 waves (wave tile 64x64 = 4x4 of 16x16x32).
// 3-slot ring LDS, prefetch depth 2, counted vmcnt (never 0 in main loop).
// 1D grid XCD swizzle (lid%8 = XCD), bn inner in groups of 8.
// MODE: 0 = bf16 C, 1 = f32 C, 2 = QKV split epilogue
//       (cols 0-1023 -> Q[b][s][h], 1024-2047 -> K[b][s][h],
//        2048-3071 -> Vt[b][h][s]; Q/K/Vt contiguous from Cout).
template <int MODE, bool HAS_BIAS>
__global__ __launch_bounds__(256, 3) void gemm_bt(
    const __bf16* __restrict__ A, const __bf16* __restrict__ Bt,
    const float* __restrict__ bias, void* __restrict__ Cout,
    int K, int lda, int ldb, int ldc, int gy, int rpx,
    float scale, long long sA, long long sB, long long sC) {
    __shared__ __align__(16) __bf16 A0[4096];
    __shared__ __align__(16) __bf16 B0[4096];
    __shared__ __align__(16) __bf16 A1[4096];
    __shared__ __align__(16) __bf16 B1[4096];
    __shared__ __align__(16) __bf16 A2[4096];
    __shared__ __align__(16) __bf16 B2[4096];

    // swizzled block mapping
    const int lid = blockIdx.x;
    const int xcd = lid & 7;
    const int j = lid >> 3;
    const int grpsz = rpx * 8;
    const int g = j / grpsz;
    const int rem = j - g * grpsz;
    const int r_local = rem >> 3;
    const int bn = g * 8 + (rem & 7);
    const int row_t = xcd * rpx + r_local;
    const int z = row_t / gy;
    const int bm = row_t - z * gy;

    const __bf16* Ab = A + (long long)z * sA;
    const __bf16* Bb = Bt + (long long)z * sB;
    const int tid = threadIdx.x;
    const int l = tid & 63, w = tid >> 6;
    const int wm = w >> 1, wn = w & 1;

    // staging: 512 chunks of 16B per tile; ch -> (kq=ch>>7, row=ch&127)
    const int ch0 = tid, ch1 = tid + 256;
    const int r0c = ch0 & 127, q0c = ch0 >> 7;
    const int r1c = ch1 & 127, q1c = ch1 >> 7;
    const __bf16* a0 = Ab + (long long)(bm * 128 + r0c) * lda + q0c * 8;
    const __bf16* a1 = Ab + (long long)(bm * 128 + r1c) * lda + q1c * 8;
    const __bf16* b0 = Bb + (long long)(bn * 128 + r0c) * ldb + q0c * 8;
    const __bf16* b1 = Bb + (long long)(bn * 128 + r1c) * ldb + q1c * 8;
    const int lo0 = ch0 * 16, lo1 = ch1 * 16;

    const int kq = l >> 4, r16 = l & 15;
    const int afo = kq * 1024 + (wm * 64 + r16) * 8;
    const int bfo = kq * 1024 + (wn * 64 + r16) * 8;

    f32x4 acc[4][4] = {};

#define STAGE(As, Bs, k0)                      \
    do {                                       \
        gl_lds16(a0 + (k0), (char*)(As) + lo0); \
        gl_lds16(a1 + (k0), (char*)(As) + lo1); \
        gl_lds16(b0 + (k0), (char*)(Bs) + lo0); \
        gl_lds16(b1 + (k0), (char*)(Bs) + lo1); \
    } while (0)

#define COMPUTE(As, Bs)                                                   \
    do {                                                                  \
        const __bf16* Af = (As) + afo;                                    \
        const __bf16* Bf = (Bs) + bfo;                                    \
        bf16x8 af[4], bfv[4];                                             \
        _Pragma("unroll") for (int i = 0; i < 4; ++i) {                   \
            af[i]  = *(const bf16x8*)(Af + i * 128);                      \
            bfv[i] = *(const bf16x8*)(Bf + i * 128);                      \
        }                                                                 \
        __builtin_amdgcn_s_setprio(1);                                    \
        _Pragma("unroll") for (int mi = 0; mi < 4; ++mi)                  \
            _Pragma("unroll") for (int ni = 0; ni < 4; ++ni)              \
                acc[mi][ni] = __builtin_amdgcn_mfma_f32_16x16x32_bf16(    \
                    af[mi], bfv[ni], acc[mi][ni], 0, 0, 0);               \
        __builtin_amdgcn_s_setprio(0);                                    \
    } while (0)

    // One ring iteration: own vmcnt wait (tile t's 4 loads are the oldest
    // beyond the wait count) -> barrier (all waves' tile-t loads landed) ->
    // reads+MFMA -> fence -> barrier (slot free for restage next iter).
#define ITER_BODY(As, Bs, VMASM)                         \
    do {                                                 \
        asm volatile(VMASM ::: "memory");                \
        __builtin_amdgcn_s_barrier();                    \
        __builtin_amdgcn_sched_barrier(0);               \
        COMPUTE(As, Bs);                                 \
        asm volatile("" ::: "memory");                   \
        __builtin_amdgcn_sched_barrier(0);               \
        __builtin_amdgcn_s_barrier();                    \
    } while (0)

#define ITER8(As, Bs, Ap, Bp, k2)                        \
    do {                                                 \
        STAGE(Ap, Bp, (k2));                             \
        ITER_BODY(As, Bs, "s_waitcnt vmcnt(8)");         \
    } while (0)
#define ITER4(As, Bs) ITER_BODY(As, Bs, "s_waitcnt vmcnt(4)")
#define ITER0(As, Bs) ITER_BODY(As, Bs, "s_waitcnt vmcnt(0)")

    const int NT = K >> 5;  // number of BK=32 tiles; NT >= 3 always here
    STAGE(A0, B0, 0);       // tile 0 -> slot 0
    STAGE(A1, B1, 32);      // tile 1 -> slot 1

    int t = 0;
    for (; t + 4 < NT; t += 3) {
        ITER8(A0, B0, A2, B2, (t + 2) * 32);
        ITER8(A1, B1, A0, B0, (t + 3) * 32);
        ITER8(A2, B2, A1, B1, (t + 4) * 32);
    }
    const int r = NT - t;  // 2, 3, or 4 (t is a multiple of 3 -> slot 0)
    if (r == 2) {
        ITER4(A0, B0);
        ITER0(A1, B1);
    } else if (r == 3) {
        ITER8(A0, B0, A2, B2, (t + 2) * 32);
        ITER4(A1, B1);
        ITER0(A2, B2);
    } else {  // r == 4
        ITER8(A0, B0, A2, B2, (t + 2) * 32);
        ITER8(A1, B1, A0, B0, (t + 3) * 32);
        ITER4(A2, B2);
        ITER0(A0, B0);
    }
#undef STAGE
#undef COMPUTE
#undef ITER_BODY
#undef ITER8
#undef ITER4
#undef ITER0

    // epilogue: D row = quad*4+reg, col = lane&15
    const int quad = l >> 4;
    if (MODE == 2) {
        __bf16* Qb = (__bf16*)Cout;
        const int part = bn >> 3;  // 0=Q 1=K 2=V
#pragma unroll
        for (int mi = 0; mi < 4; ++mi) {
            const int srow0 = bm * 128 + wm * 64 + mi * 16 + quad * 4;
            const int b = srow0 >> 11;
            const int s0 = srow0 & 2047;
#pragma unroll
            for (int ni = 0; ni < 4; ++ni) {
                const int col = bn * 128 + wn * 64 + ni * 16 + r16;
                const float bb = HAS_BIAS ? bias[col] : 0.0f;
                const int c1 = col - part * 1024;
                if (part == 2) {
                    bf16x4 o;
#pragma unroll
                    for (int rr = 0; rr < 4; ++rr) o[rr] = (__bf16)(acc[mi][ni][rr] + bb);
                    *(bf16x4*)(Qb + 33554432 + (long long)b * 2097152 +
                               (long long)c1 * 2048 + s0) = o;
                } else {
                    __bf16* dst = Qb + (long long)part * 16777216 +
                                  (long long)b * 2097152 + (long long)s0 * 1024 + c1;
#pragma unroll
                    for (int rr = 0; rr < 4; ++rr) dst[rr * 1024] = (__bf16)(acc[mi][ni][rr] + bb);
                }
            }
        }
    } else {
        const long long cbase = (long long)z * sC;
#pragma unroll
        for (int mi = 0; mi < 4; ++mi) {
#pragma unroll
            for (int ni = 0; ni < 4; ++ni) {
                const int col = bn * 128 + wn * 64 + ni * 16 + r16;
                const float bb = HAS_BIAS ? bias[col] : 0.0f;
#pragma unroll
                for (int rr = 0; rr < 4; ++rr) {
                    const int row = bm * 128 + wm * 64 + mi * 16 + quad * 4 + rr;
                    const float v = acc[mi][ni][rr] * scale + bb;
                    if (MODE == 1)
                        ((float*)Cout)[cbase + (long long)row * ldc + col] = v;
                    else
                        ((__bf16*)Cout)[cbase + (long long)row * ldc + col] = (__bf16)v;
                }
            }
        }
    }
}

extern "C" void kernel_launch(void* const* d_in, const int* in_sizes, int n_in,
                              void* d_out, int out_size, void* d_ws, size_t ws_size,
                              hipStream_t stream) {
    const float* x  = (const float*)d_in[0];
    const float* wq = (const float*)d_in[1];
    const float* bq = (const float*)d_in[2];
    const float* wk = (const float*)d_in[3];
    const float* bk = (const float*)d_in[4];
    const float* wv = (const float*)d_in[5];
    const float* bv = (const float*)d_in[6];
    const float* wo = (const float*)d_in[7];
    const float* bo = (const float*)d_in[8];
    float* out = (float*)d_out;

    // ws layout (bf16 elems), ~200 MiB total.
    // Q, Kb, Vt must be contiguous in that order (MODE 2 epilogue).
    __bf16* ws  = (__bf16*)d_ws;
    __bf16* Xb  = ws;                   // 16,777,216 (phase 1; dead after QKV)
    __bf16* E   = ws;                   // 33,554,432 (phase 2, reuses Xb)
    __bf16* Q   = ws + 33554432;        // 16,777,216
    __bf16* Kb  = ws + 50331648;        // 16,777,216
    __bf16* Vt  = ws + 67108864;        // 16,777,216
    __bf16* Ctx = ws + 83886080;        // 16,777,216
    __bf16* WT  = ws + 100663296;       // 4,194,304
    float*  bc  = (float*)(ws + 104857600);  // 3072 fp32

    k_convert<<<8192, 256, 0, stream>>>(x, Xb);
    k_transpose_w<<<dim3(16, 16, 4), 256, 0, stream>>>(wq, wk, wv, wo, WT);
    k_bcat<<<12, 256, 0, stream>>>(bq, bk, bv, bc);

    // Fused QKV: [16384,3072] = Xb @ WT^T + bcat; writes Q, K, V^T
    // 128 row-tiles, 24 bn-tiles -> 3072 blocks; gy=128, rpx=16
    gemm_bt<2, true><<<3072, 256, 0, stream>>>(
        Xb, WT, bc, Q, 1024, 1024, 1024, 0, 128, 16, 1.0f, 0, 0, 0);

    // E[b] = Q[b] @ K[b]^T / 32   row_t=128 (16/z), bn=16 -> 2048 blocks
    gemm_bt<0, false><<<2048, 256, 0, stream>>>(
        Q, Kb, nullptr, E, 1024, 1024, 1024, 2048, 16, 16,
        0.03125f, 2097152, 2097152, 4194304);

    k_softmax<<<16384, 256, 0, stream>>>(E);

    // Ctx[b] = P[b] @ Vt[b]^T    row_t=128, bn=8 -> 1024 blocks
    gemm_bt<0, false><<<1024, 256, 0, stream>>>(
        E, Vt, nullptr, Ctx, 2048, 2048, 2048, 1024, 16, 16,
        1.0f, 4194304, 2097152, 2097152);

    // out = Ctx @ Wo^T + bo (fp32)  row_t=128, bn=8 -> 1024 blocks
    gemm_bt<1, true><<<1024, 256, 0, stream>>>(
        Ctx, WT + 3145728, bo, out, 1024, 1024, 1024, 1024, 128, 16,
        1.0f, 0, 0, 0);
}

// Round 2
// 509.047 us; speedup vs baseline: 1.3726x; 1.3726x over previous
//
#include <hip/hip_runtime.h>
#include <hip/hip_bf16.h>

// SpecAttn: out = softmax((x@Wq+bq)(x@Wk+bk)^T / 32) @ (x@Wv+bv) @ Wo + bo
// B=8, S=2048, H=1024. bf16 MFMA everywhere, fp32 accumulate.
// R7: 256x256 8-phase GEMM (T3+T4+T5 port of the HK/m201 schedule, plain HIP).
//     BM=BN=256, BK=64, 8 waves (2Mx4N), per-wave 128x64 output (acc[8][4]).
//     LDS 128KB: A/B double-buffered 256x64 bf16 tiles in [kq(8)][row(256)][8]
//     layout (16B/lane-contiguous b128 frag reads -> 0 bank conflicts, no
//     swizzle needed). Per phase: {4-12 ds_read || stage 1 half-tile via
//     global_load_lds -> s_barrier -> lgkmcnt(0) -> setprio(1)+16 MFMA ->
//     s_barrier}. Counted vmcnt(4) ONLY at phases 4 and 8 (ledger: forces
//     exactly the tiles consumed by the next 4 phases; 12 VMEM max in
//     flight); vmcnt(0) only in the tail iteration. 1 block/CU.

typedef __attribute__((ext_vector_type(8))) __bf16 bf16x8;
typedef __attribute__((ext_vector_type(4))) __bf16 bf16x4;
typedef __attribute__((ext_vector_type(4))) float  f32x4;
typedef __attribute__((ext_vector_type(8))) float  f32x8;

__device__ __forceinline__ void gl_lds16(const void* g, void* l) {
    __builtin_amdgcn_global_load_lds(
        (__attribute__((address_space(1))) const void*)g,
        (__attribute__((address_space(3))) void*)l, 16, 0, 0);
}

// ---------------- fp32 -> bf16 convert (x) ----------------
__global__ __launch_bounds__(256) void k_convert(const float* __restrict__ in,
                                                 __bf16* __restrict__ out) {
    const int i = blockIdx.x * 256 + threadIdx.x;   // 8 elems/thread, exact fit
    f32x8 a = *((const f32x8*)in + i);
    bf16x8 o;
#pragma unroll
    for (int j = 0; j < 8; ++j) o[j] = (__bf16)a[j];
    *((bf16x8*)out + i) = o;
}

// --- fp32 W[k][n] -> bf16 Wt[n][k] (1024x1024), z selects weight ---
__global__ __launch_bounds__(256) void k_transpose_w(
    const float* __restrict__ w0, const float* __restrict__ w1,
    const float* __restrict__ w2, const float* __restrict__ w3,
    __bf16* __restrict__ Wt) {
    const int z = blockIdx.z;
    const float* W = (z == 0) ? w0 : (z == 1) ? w1 : (z == 2) ? w2 : w3;
    __bf16* Wo = Wt + (long long)z * 1048576;
    __shared__ float t[64][65];
    const int tid = threadIdx.x;
    const int c4 = (tid & 15) * 4, r0 = tid >> 4;
    const int bx = blockIdx.x * 64, by = blockIdx.y * 64;
#pragma unroll
    for (int p = 0; p < 4; ++p) {
        const int r = r0 + p * 16;
        f32x4 v = *(const f32x4*)(W + (long long)(by + r) * 1024 + bx + c4);
#pragma unroll
        for (int j = 0; j < 4; ++j) t[r][c4 + j] = v[j];
    }
    __syncthreads();
#pragma unroll
    for (int p = 0; p < 4; ++p) {
        const int r = r0 + p * 16;
        bf16x4 o;
#pragma unroll
        for (int j = 0; j < 4; ++j) o[j] = (__bf16)t[c4 + j][r];
        *(bf16x4*)(Wo + (long long)(bx + r) * 1024 + by + c4) = o;
    }
}

// ------------- concat biases into bcat[3072] fp32 -------------
__global__ __launch_bounds__(256) void k_bcat(const float* __restrict__ bq,
                                              const float* __restrict__ bk,
                                              const float* __restrict__ bv,
                                              float* __restrict__ bc) {
    const int i = blockIdx.x * 256 + threadIdx.x;  // grid 12 -> 3072
    const float* s = (i < 1024) ? bq : (i < 2048 ? bk : bv);
    bc[i] = s[i & 1023];
}

// ------------- row softmax over 2048 cols, in place, bf16 -------------
__global__ __launch_bounds__(256) void k_softmax(__bf16* __restrict__ E) {
    __bf16* p = E + (long long)blockIdx.x * 2048;
    const int tid = threadIdx.x, l = tid & 63, w = tid >> 6;
    bf16x8 vb = *((const bf16x8*)p + tid);
    float v[8];
#pragma unroll
    for (int i = 0; i < 8; ++i) v[i] = (float)vb[i];
    float m = v[0];
#pragma unroll
    for (int i = 1; i < 8; ++i) m = fmaxf(m, v[i]);
    for (int off = 32; off > 0; off >>= 1) m = fmaxf(m, __shfl_xor(m, off));
    __shared__ float redm[4], reds[4];
    if (l == 0) redm[w] = m;
    __syncthreads();
    m = fmaxf(fmaxf(redm[0], redm[1]), fmaxf(redm[2], redm[3]));
    float e[8], s = 0.f;
#pragma unroll
    for (int i = 0; i < 8; ++i) { e[i] = __expf(v[i] - m); s += e[i]; }
    for (int off = 32; off > 0; off >>= 1) s += __shfl_xor(s, off);
    if (l == 0) reds[w] = s;
    __syncthreads();
    s = reds[0] + reds[1] + reds[2] + reds[3];
    const float inv = 1.0f / s;
    bf16x8 o;
#pragma unroll
    for (int i = 0; i < 8; ++i) o[i] = (__bf16)(e[i] * inv);
    *((bf16x8*)p + tid) = o;
}

// ------------- GEMM: C[z] = A[z] @ Bt[z]^T * scale (+bias) -------------
// 256x256 tile, BK=64, 8 waves (2x4), wave tile 128x64, 8-phase schedule.
// LDS tile layout: [kq 0..7][row 0..255][8 bf16]; wave w stages kq=w slab.
// Grid: nwg = rowtiles*bnc, nwg%8==0. lid&7 = XCD, bn-inner per XCD.
// MODE: 0 = bf16 C, 1 = f32 C, 2 = QKV split epilogue
//       (cols 0-1023 -> Q[b][s][h], 1024-2047 -> K[b][s][h],
//        2048-3071 -> Vt[b][h][s]; Q/K/Vt contiguous from Cout).
template <int MODE, bool HAS_BIAS>
__global__ __launch_bounds__(512, 2) void gemm_bt(
    const __bf16* __restrict__ A, const __bf16* __restrict__ Bt,
    const float* __restrict__ bias, void* __restrict__ Cout,
    int K, int lda, int ldb, int ldc, int gy, int rpx, int bnc,
    float scale, long long sA, long long sB, long long sC) {
    __shared__ __align__(16) __bf16 Abuf0[16384];
    __shared__ __align__(16) __bf16 Bbuf0[16384];
    __shared__ __align__(16) __bf16 Abuf1[16384];
    __shared__ __align__(16) __bf16 Bbuf1[16384];

    // swizzled block mapping
    const int lid = blockIdx.x;
    const int xcd = lid & 7;
    const int jj = lid >> 3;
    const int bn = jj % bnc;
    const int rt = xcd * rpx + jj / bnc;
    const int z = rt / gy;
    const int bm = rt - z * gy;

    const __bf16* Ab = A + (long long)z * sA;
    const __bf16* Bb = Bt + (long long)z * sB;

    const int tid = threadIdx.x;
    const int l = tid & 63, w = tid >> 6;   // lane, wave 0..7
    const int wm = w >> 2, wn = w & 3;      // 2 x 4 wave grid

    // staging: wave w covers k-quad kq=w (k cols w*8..w*8+7); lane = row.
    // chunk (h,i): rows h*128 + i*64 .. +63.
    const __bf16* aS = Ab + (long long)(bm * 256 + l) * lda + w * 8;
    const __bf16* bS = Bb + (long long)(bn * 256 + l) * ldb + w * 8;
    const long long a64 = (long long)lda * 64;
    const long long b64 = (long long)ldb * 64;

    // ds-read fragment offsets (elements): lane l -> row wm*128 + (l&15),
    // k-quad (l>>4) within k-half; frag (mi,kh) at + mi*128 + kh*8192.
    const int r16 = l & 15, kq4 = l >> 4;
    const int aro = kq4 * 2048 + (wm * 128 + r16) * 8;
    const int bro = kq4 * 2048 + (wn * 64 + r16) * 8;

    f32x4 acc[8][4] = {};
    bf16x8 bf[4][2];

#define ST_A(buf, h, i, t)                                                 \
    gl_lds16(aS + ((h) * 2 + (i)) * a64 + (long long)(t) * 64,             \
             (char*)(buf) + w * 4096 + ((h) * 128 + (i) * 64) * 16)
#define ST_B(buf, h, i, t)                                                 \
    gl_lds16(bS + ((h) * 2 + (i)) * b64 + (long long)(t) * 64,             \
             (char*)(buf) + w * 4096 + ((h) * 128 + (i) * 64) * 16)

#define RD_B(buf)                                                          \
    do {                                                                   \
        _Pragma("unroll") for (int ni = 0; ni < 4; ++ni) {                 \
            bf[ni][0] = *(const bf16x8*)((buf) + bro + ni * 128);          \
            bf[ni][1] = *(const bf16x8*)((buf) + bro + 8192 + ni * 128);   \
        }                                                                  \
    } while (0)

#define WV4 asm volatile("s_waitcnt vmcnt(4)" ::: "memory")
#define WV0 asm volatile("s_waitcnt vmcnt(0)" ::: "memory")
#define NOW ((void)0)

// One phase: ds-read A mi-pair (and B on p==0) || stage -> barrier ->
// lgkmcnt(0) -> setprio(1)+16 MFMA -> [vmcnt] -> barrier.
#define PHASE(Abuf, p, RB, RBUF, STAGES, WAIT)                                 \
    do {                                                                      \
        bf16x8 af0k0 = *(const bf16x8*)((Abuf) + aro + (2 * (p)) * 128);       \
        bf16x8 af0k1 = *(const bf16x8*)((Abuf) + aro + 8192 + (2 * (p)) * 128);\
        bf16x8 af1k0 = *(const bf16x8*)((Abuf) + aro + (2 * (p) + 1) * 128);   \
        bf16x8 af1k1 = *(const bf16x8*)((Abuf) + aro + 8192 + (2*(p)+1) * 128);\
        if (RB) RD_B(RBUF);                                                   \
        STAGES;                                                               \
        __builtin_amdgcn_s_barrier();                                         \
        asm volatile("s_waitcnt lgkmcnt(0)" ::: "memory");                    \
        __builtin_amdgcn_sched_barrier(0);                                    \
        __builtin_amdgcn_s_setprio(1);                                        \
        _Pragma("unroll") for (int ni = 0; ni < 4; ++ni) {                    \
            acc[2 * (p)][ni] = __builtin_amdgcn_mfma_f32_16x16x32_bf16(       \
                af0k0, bf[ni][0], acc[2 * (p)][ni], 0, 0, 0);                 \
            acc[2 * (p)][ni] = __builtin_amdgcn_mfma_f32_16x16x32_bf16(       \
                af0k1, bf[ni][1], acc[2 * (p)][ni], 0, 0, 0);                 \
            acc[2 * (p) + 1][ni] = __builtin_amdgcn_mfma_f32_16x16x32_bf16(   \
                af1k0, bf[ni][0], acc[2 * (p) + 1][ni], 0, 0, 0);             \
            acc[2 * (p) + 1][ni] = __builtin_amdgcn_mfma_f32_16x16x32_bf16(   \
                af1k1, bf[ni][1], acc[2 * (p) + 1][ni], 0, 0, 0);             \
        }                                                                     \
        __builtin_amdgcn_s_setprio(0);                                        \
        WAIT;                                                                 \
        __builtin_amdgcn_sched_barrier(0);                                    \
        __builtin_amdgcn_s_barrier();                                         \
    } while (0)

    // Prologue: stage B(0), A(0), B(1); force B(0),A(0) (keep B(1) in flight).
    ST_B(Bbuf0, 0, 0, 0); ST_B(Bbuf0, 0, 1, 0); ST_B(Bbuf0, 1, 0, 0); ST_B(Bbuf0, 1, 1, 0);
    ST_A(Abuf0, 0, 0, 0); ST_A(Abuf0, 0, 1, 0); ST_A(Abuf0, 1, 0, 0); ST_A(Abuf0, 1, 1, 0);
    ST_B(Bbuf1, 0, 0, 1); ST_B(Bbuf1, 0, 1, 1); ST_B(Bbuf1, 1, 0, 1); ST_B(Bbuf1, 1, 1, 1);
    WV4;
    __builtin_amdgcn_s_barrier();

    const int NT = K >> 6;  // K-tiles of 64; NT even, >= 4 for all dispatches
    // Main iters: compute tiles (t0, t0+1); stage A(t0+1), B/A(t0+2), B(t0+3).
    for (int t0 = 0; t0 + 3 < NT; t0 += 2) {
        PHASE(Abuf0, 0, 1, Bbuf0,
              (ST_A(Abuf1, 0, 0, t0 + 1), ST_A(Abuf1, 0, 1, t0 + 1),
               ST_A(Abuf1, 1, 0, t0 + 1), ST_A(Abuf1, 1, 1, t0 + 1)), NOW);
        PHASE(Abuf0, 1, 0, Bbuf0,
              (ST_B(Bbuf0, 0, 0, t0 + 2), ST_B(Bbuf0, 0, 1, t0 + 2)), NOW);
        PHASE(Abuf0, 2, 0, Bbuf0,
              (ST_B(Bbuf0, 1, 0, t0 + 2), ST_B(Bbuf0, 1, 1, t0 + 2)), NOW);
        PHASE(Abuf0, 3, 0, Bbuf0, NOW, WV4);
        PHASE(Abuf1, 0, 1, Bbuf1,
              (ST_A(Abuf0, 0, 0, t0 + 2), ST_A(Abuf0, 0, 1, t0 + 2)), NOW);
        PHASE(Abuf1, 1, 0, Bbuf1,
              (ST_A(Abuf0, 1, 0, t0 + 2), ST_A(Abuf0, 1, 1, t0 + 2)), NOW);
        PHASE(Abuf1, 2, 0, Bbuf1,
              (ST_B(Bbuf1, 0, 0, t0 + 3), ST_B(Bbuf1, 0, 1, t0 + 3)), NOW);
        PHASE(Abuf1, 3, 0, Bbuf1,
              (ST_B(Bbuf1, 1, 0, t0 + 3), ST_B(Bbuf1, 1, 1, t0 + 3)), WV4);
    }
    // Tail iter: t0 = NT-2. Stage only A(NT-1); drain at phase 4.
    {
        const int t0 = NT - 2;
        PHASE(Abuf0, 0, 1, Bbuf0,
              (ST_A(Abuf1, 0, 0, t0 + 1), ST_A(Abuf1, 0, 1, t0 + 1),
               ST_A(Abuf1, 1, 0, t0 + 1), ST_A(Abuf1, 1, 1, t0 + 1)), NOW);
        PHASE(Abuf0, 1, 0, Bbuf0, NOW, NOW);
        PHASE(Abuf0, 2, 0, Bbuf0, NOW, NOW);
        PHASE(Abuf0, 3, 0, Bbuf0, NOW, WV0);
        PHASE(Abuf1, 0, 1, Bbuf1, NOW, NOW);
        PHASE(Abuf1, 1, 0, Bbuf1, NOW, NOW);
        PHASE(Abuf1, 2, 0, Bbuf1, NOW, NOW);
        PHASE(Abuf1, 3, 0, Bbuf1, NOW, NOW);
    }
#undef ST_A
#undef ST_B
#undef RD_B
#undef WV4
#undef WV0
#undef NOW
#undef PHASE

    // epilogue: D row = (l>>4)*4+reg, col = lane&15 within each 16x16 frag
    const int quad = kq4;
    if (MODE == 2) {
        __bf16* Qb = (__bf16*)Cout;
        const int part = bn >> 2;  // 0=Q 1=K 2=V  (256-col tiles, 4 per part)
#pragma unroll
        for (int mi = 0; mi < 8; ++mi) {
            const int srow0 = bm * 256 + wm * 128 + mi * 16 + quad * 4;
            const int b = srow0 >> 11;
            const int s0 = srow0 & 2047;
#pragma unroll
            for (int ni = 0; ni < 4; ++ni) {
                const int col = bn * 256 + wn * 64 + ni * 16 + r16;
                const float bb = HAS_BIAS ? bias[col] : 0.0f;
                const int c1 = col - part * 1024;
                if (part == 2) {
                    bf16x4 o;
#pragma unroll
                    for (int rr = 0; rr < 4; ++rr) o[rr] = (__bf16)(acc[mi][ni][rr] + bb);
                    *(bf16x4*)(Qb + 33554432 + (long long)b * 2097152 +
                               (long long)c1 * 2048 + s0) = o;
                } else {
                    __bf16* dst = Qb + (long long)part * 16777216 +
                                  (long long)b * 2097152 + (long long)s0 * 1024 + c1;
#pragma unroll
                    for (int rr = 0; rr < 4; ++rr) dst[rr * 1024] = (__bf16)(acc[mi][ni][rr] + bb);
                }
            }
        }
    } else {
        const long long cbase = (long long)z * sC;
#pragma unroll
        for (int mi = 0; mi < 8; ++mi) {
#pragma unroll
            for (int ni = 0; ni < 4; ++ni) {
                const int col = bn * 256 + wn * 64 + ni * 16 + r16;
                const float bb = HAS_BIAS ? bias[col] : 0.0f;
#pragma unroll
                for (int rr = 0; rr < 4; ++rr) {
                    const int row = bm * 256 + wm * 128 + mi * 16 + quad * 4 + rr;
                    const float v = acc[mi][ni][rr] * scale + bb;
                    if (MODE == 1)
                        ((float*)Cout)[cbase + (long long)row * ldc + col] = v;
                    else
                        ((__bf16*)Cout)[cbase + (long long)row * ldc + col] = (__bf16)v;
                }
            }
        }
    }
}

extern "C" void kernel_launch(void* const* d_in, const int* in_sizes, int n_in,
                              void* d_out, int out_size, void* d_ws, size_t ws_size,
                              hipStream_t stream) {
    const float* x  = (const float*)d_in[0];
    const float* wq = (const float*)d_in[1];
    const float* bq = (const float*)d_in[2];
    const float* wk = (const float*)d_in[3];
    const float* bk = (const float*)d_in[4];
    const float* wv = (const float*)d_in[5];
    const float* bv = (const float*)d_in[6];
    const float* wo = (const float*)d_in[7];
    const float* bo = (const float*)d_in[8];
    float* out = (float*)d_out;

    // ws layout (bf16 elems), ~200 MiB total.
    // Q, Kb, Vt must be contiguous in that order (MODE 2 epilogue).
    __bf16* ws  = (__bf16*)d_ws;
    __bf16* Xb  = ws;                   // 16,777,216 (phase 1; dead after QKV)
    __bf16* E   = ws;                   // 33,554,432 (phase 2, reuses Xb)
    __bf16* Q   = ws + 33554432;        // 16,777,216
    __bf16* Kb  = ws + 50331648;        // 16,777,216
    __bf16* Vt  = ws + 67108864;        // 16,777,216
    __bf16* Ctx = ws + 83886080;        // 16,777,216
    __bf16* WT  = ws + 100663296;       // 4,194,304
    float*  bc  = (float*)(ws + 104857600);  // 3072 fp32

    k_convert<<<8192, 256, 0, stream>>>(x, Xb);
    k_transpose_w<<<dim3(16, 16, 4), 256, 0, stream>>>(wq, wk, wv, wo, WT);
    k_bcat<<<12, 256, 0, stream>>>(bq, bk, bv, bc);

    // Fused QKV: [16384,3072] = Xb @ WT^T + bcat; writes Q, K, V^T
    // rowtiles=64, bnc=12 -> 768 blocks; gy=64 (z=0), rpx=8
    gemm_bt<2, true><<<768, 512, 0, stream>>>(
        Xb, WT, bc, Q, 1024, 1024, 1024, 0, 64, 8, 12, 1.0f, 0, 0, 0);

    // E[b] = Q[b] @ K[b]^T / 32   rowtiles=64 (8/z), bnc=8 -> 512 blocks
    gemm_bt<0, false><<<512, 512, 0, stream>>>(
        Q, Kb, nullptr, E, 1024, 1024, 1024, 2048, 8, 8, 8,
        0.03125f, 2097152, 2097152, 4194304);

    k_softmax<<<16384, 256, 0, stream>>>(E);

    // Ctx[b] = P[b] @ Vt[b]^T    rowtiles=64, bnc=4 -> 256 blocks
    gemm_bt<0, false><<<256, 512, 0, stream>>>(
        E, Vt, nullptr, Ctx, 2048, 2048, 2048, 1024, 8, 8, 4,
        1.0f, 4194304, 2097152, 2097152);

    // out = Ctx @ Wo^T + bo (fp32)  rowtiles=64, bnc=4 -> 256 blocks
    gemm_bt<1, true><<<256, 512, 0, stream>>>(
        Ctx, WT + 3145728, bo, out, 1024, 1024, 1024, 1024, 64, 8, 4,
        1.0f, 0, 0, 0);
}

// Round 3
// 456.629 us; speedup vs baseline: 1.5302x; 1.1148x over previous
//
#include <hip/hip_runtime.h>
#include <hip/hip_bf16.h>

// SpecAttn: out = softmax((x@Wq+bq)(x@Wk+bk)^T / 32) @ (x@Wv+bv) @ Wo + bo
// B=8, S=2048, H=1024. bf16 MFMA everywhere, fp32 accumulate.
// R8: R7's 8-phase 256x256 schedule + T2 swizzle staging fix.
//     R7 staged with lane=row (stride-2048B gather: 64 cachelines per
//     global_load_lds -> TA/L1 transaction-bound, MfmaUtil stuck at 28%).
//     R8: LDS tiles linear row-major [row256][64], staging lanes cover
//     contiguous 128B rows (8 lines/gl_lds, coalesced); global source is
//     INVERSE-swizzled (chunk c' = c ^ (row&3)) and ds_read applies the
//     same XOR (rule #21 both-sides involution). The 2-bit XOR avoids the
//     kh bit so frag offsets stay compile-time. Reads go 0-conflict ->
//     ~4-way (m201's residual level); writes stay linear/conflict-free.
//     Phase schedule, vmcnt ledger (WV4 at ph4/ph8 only), setprio, barriers
//     identical to R7.

typedef __attribute__((ext_vector_type(8))) __bf16 bf16x8;
typedef __attribute__((ext_vector_type(4))) __bf16 bf16x4;
typedef __attribute__((ext_vector_type(4))) float  f32x4;
typedef __attribute__((ext_vector_type(8))) float  f32x8;

__device__ __forceinline__ void gl_lds16(const void* g, void* l) {
    __builtin_amdgcn_global_load_lds(
        (__attribute__((address_space(1))) const void*)g,
        (__attribute__((address_space(3))) void*)l, 16, 0, 0);
}

// ---------------- fp32 -> bf16 convert (x) ----------------
__global__ __launch_bounds__(256) void k_convert(const float* __restrict__ in,
                                                 __bf16* __restrict__ out) {
    const int i = blockIdx.x * 256 + threadIdx.x;   // 8 elems/thread, exact fit
    f32x8 a = *((const f32x8*)in + i);
    bf16x8 o;
#pragma unroll
    for (int j = 0; j < 8; ++j) o[j] = (__bf16)a[j];
    *((bf16x8*)out + i) = o;
}

// --- fp32 W[k][n] -> bf16 Wt[n][k] (1024x1024), z selects weight ---
__global__ __launch_bounds__(256) void k_transpose_w(
    const float* __restrict__ w0, const float* __restrict__ w1,
    const float* __restrict__ w2, const float* __restrict__ w3,
    __bf16* __restrict__ Wt) {
    const int z = blockIdx.z;
    const float* W = (z == 0) ? w0 : (z == 1) ? w1 : (z == 2) ? w2 : w3;
    __bf16* Wo = Wt + (long long)z * 1048576;
    __shared__ float t[64][65];
    const int tid = threadIdx.x;
    const int c4 = (tid & 15) * 4, r0 = tid >> 4;
    const int bx = blockIdx.x * 64, by = blockIdx.y * 64;
#pragma unroll
    for (int p = 0; p < 4; ++p) {
        const int r = r0 + p * 16;
        f32x4 v = *(const f32x4*)(W + (long long)(by + r) * 1024 + bx + c4);
#pragma unroll
        for (int j = 0; j < 4; ++j) t[r][c4 + j] = v[j];
    }
    __syncthreads();
#pragma unroll
    for (int p = 0; p < 4; ++p) {
        const int r = r0 + p * 16;
        bf16x4 o;
#pragma unroll
        for (int j = 0; j < 4; ++j) o[j] = (__bf16)t[c4 + j][r];
        *(bf16x4*)(Wo + (long long)(bx + r) * 1024 + by + c4) = o;
    }
}

// ------------- concat biases into bcat[3072] fp32 -------------
__global__ __launch_bounds__(256) void k_bcat(const float* __restrict__ bq,
                                              const float* __restrict__ bk,
                                              const float* __restrict__ bv,
                                              float* __restrict__ bc) {
    const int i = blockIdx.x * 256 + threadIdx.x;  // grid 12 -> 3072
    const float* s = (i < 1024) ? bq : (i < 2048 ? bk : bv);
    bc[i] = s[i & 1023];
}

// ------------- row softmax over 2048 cols, in place, bf16 -------------
__global__ __launch_bounds__(256) void k_softmax(__bf16* __restrict__ E) {
    __bf16* p = E + (long long)blockIdx.x * 2048;
    const int tid = threadIdx.x, l = tid & 63, w = tid >> 6;
    bf16x8 vb = *((const bf16x8*)p + tid);
    float v[8];
#pragma unroll
    for (int i = 0; i < 8; ++i) v[i] = (float)vb[i];
    float m = v[0];
#pragma unroll
    for (int i = 1; i < 8; ++i) m = fmaxf(m, v[i]);
    for (int off = 32; off > 0; off >>= 1) m = fmaxf(m, __shfl_xor(m, off));
    __shared__ float redm[4], reds[4];
    if (l == 0) redm[w] = m;
    __syncthreads();
    m = fmaxf(fmaxf(redm[0], redm[1]), fmaxf(redm[2], redm[3]));
    float e[8], s = 0.f;
#pragma unroll
    for (int i = 0; i < 8; ++i) { e[i] = __expf(v[i] - m); s += e[i]; }
    for (int off = 32; off > 0; off >>= 1) s += __shfl_xor(s, off);
    if (l == 0) reds[w] = s;
    __syncthreads();
    s = reds[0] + reds[1] + reds[2] + reds[3];
    const float inv = 1.0f / s;
    bf16x8 o;
#pragma unroll
    for (int i = 0; i < 8; ++i) o[i] = (__bf16)(e[i] * inv);
    *((bf16x8*)p + tid) = o;
}

// ------------- GEMM: C[z] = A[z] @ Bt[z]^T * scale (+bias) -------------
// 256x256 tile, BK=64, 8 waves (2x4), wave tile 128x64, 8-phase schedule.
// LDS tile layout: [row 0..255][64 cols], chunk swizzle c' = c ^ (row&3).
// Staging: thread t -> LDS linear t*16 (+j*8192), global row t>>3 (+64j),
//          chunk (t&7)^((t>>3)&3)  -> coalesced 128B/row, 8 lines per wave.
// Grid: nwg = rowtiles*bnc, nwg%8==0. lid&7 = XCD, bn-inner per XCD.
// MODE: 0 = bf16 C, 1 = f32 C, 2 = QKV split epilogue
//       (cols 0-1023 -> Q[b][s][h], 1024-2047 -> K[b][s][h],
//        2048-3071 -> Vt[b][h][s]; Q/K/Vt contiguous from Cout).
template <int MODE, bool HAS_BIAS>
__global__ __launch_bounds__(512, 2) void gemm_bt(
    const __bf16* __restrict__ A, const __bf16* __restrict__ Bt,
    const float* __restrict__ bias, void* __restrict__ Cout,
    int K, int lda, int ldb, int ldc, int gy, int rpx, int bnc,
    float scale, long long sA, long long sB, long long sC) {
    __shared__ __align__(16) __bf16 Abuf0[16384];
    __shared__ __align__(16) __bf16 Bbuf0[16384];
    __shared__ __align__(16) __bf16 Abuf1[16384];
    __shared__ __align__(16) __bf16 Bbuf1[16384];

    // swizzled block mapping
    const int lid = blockIdx.x;
    const int xcd = lid & 7;
    const int jj = lid >> 3;
    const int bn = jj % bnc;
    const int rt = xcd * rpx + jj / bnc;
    const int z = rt / gy;
    const int bm = rt - z * gy;

    const __bf16* Ab = A + (long long)z * sA;
    const __bf16* Bb = Bt + (long long)z * sB;

    const int tid = threadIdx.x;
    const int l = tid & 63, w = tid >> 6;   // lane, wave 0..7
    const int wm = w >> 2, wn = w & 3;      // 2 x 4 wave grid

    // staging: thread t covers rows (t>>3)+64j, global chunk (t&7)^((t>>3)&3)
    const int rA = tid >> 3;
    const int cswz = (tid & 7) ^ (rA & 3);
    const __bf16* aSg = Ab + (long long)(bm * 256 + rA) * lda + cswz * 8;
    const __bf16* bSg = Bb + (long long)(bn * 256 + rA) * ldb + cswz * 8;
    const long long a64 = (long long)lda * 64;
    const long long b64 = (long long)ldb * 64;
    const int ldst = tid * 16;              // LDS byte base (linear)

    // ds-read fragment offsets (elements): row stride 64, chunk XOR (r16&3).
    // A frag (mi,kh): aro + mi*1024 + kh*32 ; B frag (ni,kh): bro + ni*1024 + kh*32
    const int r16 = l & 15, kq4 = l >> 4;
    const int swz = kq4 ^ (r16 & 3);
    const int aro = (wm * 128 + r16) * 64 + swz * 8;
    const int bro = (wn * 64 + r16) * 64 + swz * 8;

    f32x4 acc[8][4] = {};
    bf16x8 bf[4][2];

#define ST_A(buf, j, t)                                                    \
    gl_lds16(aSg + (j) * a64 + (long long)(t) * 64,                        \
             (char*)(buf) + ldst + (j) * 8192)
#define ST_B(buf, j, t)                                                    \
    gl_lds16(bSg + (j) * b64 + (long long)(t) * 64,                        \
             (char*)(buf) + ldst + (j) * 8192)

#define RD_B(buf)                                                          \
    do {                                                                   \
        _Pragma("unroll") for (int ni = 0; ni < 4; ++ni) {                 \
            bf[ni][0] = *(const bf16x8*)((buf) + bro + ni * 1024);         \
            bf[ni][1] = *(const bf16x8*)((buf) + bro + ni * 1024 + 32);    \
        }                                                                  \
    } while (0)

#define WV4 asm volatile("s_waitcnt vmcnt(4)" ::: "memory")
#define WV0 asm volatile("s_waitcnt vmcnt(0)" ::: "memory")
#define NOW ((void)0)

// One phase: ds-read A mi-pair (and B on p==0) || stage -> barrier ->
// lgkmcnt(0) -> setprio(1)+16 MFMA -> [vmcnt] -> barrier.
#define PHASE(Abuf, p, RB, RBUF, STAGES, WAIT)                                 \
    do {                                                                      \
        bf16x8 af0k0 = *(const bf16x8*)((Abuf) + aro + (2 * (p)) * 1024);      \
        bf16x8 af0k1 = *(const bf16x8*)((Abuf) + aro + (2 * (p)) * 1024 + 32); \
        bf16x8 af1k0 = *(const bf16x8*)((Abuf) + aro + (2 * (p) + 1) * 1024);  \
        bf16x8 af1k1 = *(const bf16x8*)((Abuf) + aro + (2*(p)+1) * 1024 + 32); \
        if (RB) RD_B(RBUF);                                                   \
        STAGES;                                                               \
        __builtin_amdgcn_s_barrier();                                         \
        asm volatile("s_waitcnt lgkmcnt(0)" ::: "memory");                    \
        __builtin_amdgcn_sched_barrier(0);                                    \
        __builtin_amdgcn_s_setprio(1);                                        \
        _Pragma("unroll") for (int ni = 0; ni < 4; ++ni) {                    \
            acc[2 * (p)][ni] = __builtin_amdgcn_mfma_f32_16x16x32_bf16(       \
                af0k0, bf[ni][0], acc[2 * (p)][ni], 0, 0, 0);                 \
            acc[2 * (p)][ni] = __builtin_amdgcn_mfma_f32_16x16x32_bf16(       \
                af0k1, bf[ni][1], acc[2 * (p)][ni], 0, 0, 0);                 \
            acc[2 * (p) + 1][ni] = __builtin_amdgcn_mfma_f32_16x16x32_bf16(   \
                af1k0, bf[ni][0], acc[2 * (p) + 1][ni], 0, 0, 0);             \
            acc[2 * (p) + 1][ni] = __builtin_amdgcn_mfma_f32_16x16x32_bf16(   \
                af1k1, bf[ni][1], acc[2 * (p) + 1][ni], 0, 0, 0);             \
        }                                                                     \
        __builtin_amdgcn_s_setprio(0);                                        \
        WAIT;                                                                 \
        __builtin_amdgcn_sched_barrier(0);                                    \
        __builtin_amdgcn_s_barrier();                                         \
    } while (0)

    // Prologue: stage B(0), A(0), B(1); force B(0),A(0) (keep B(1) in flight).
    ST_B(Bbuf0, 0, 0); ST_B(Bbuf0, 1, 0); ST_B(Bbuf0, 2, 0); ST_B(Bbuf0, 3, 0);
    ST_A(Abuf0, 0, 0); ST_A(Abuf0, 1, 0); ST_A(Abuf0, 2, 0); ST_A(Abuf0, 3, 0);
    ST_B(Bbuf1, 0, 1); ST_B(Bbuf1, 1, 1); ST_B(Bbuf1, 2, 1); ST_B(Bbuf1, 3, 1);
    WV4;
    __builtin_amdgcn_s_barrier();

    const int NT = K >> 6;  // K-tiles of 64; NT even, >= 4 for all dispatches
    // Main iters: compute tiles (t0, t0+1); stage A(t0+1), B/A(t0+2), B(t0+3).
    for (int t0 = 0; t0 + 3 < NT; t0 += 2) {
        PHASE(Abuf0, 0, 1, Bbuf0,
              (ST_A(Abuf1, 0, t0 + 1), ST_A(Abuf1, 1, t0 + 1),
               ST_A(Abuf1, 2, t0 + 1), ST_A(Abuf1, 3, t0 + 1)), NOW);
        PHASE(Abuf0, 1, 0, Bbuf0,
              (ST_B(Bbuf0, 0, t0 + 2), ST_B(Bbuf0, 1, t0 + 2)), NOW);
        PHASE(Abuf0, 2, 0, Bbuf0,
              (ST_B(Bbuf0, 2, t0 + 2), ST_B(Bbuf0, 3, t0 + 2)), NOW);
        PHASE(Abuf0, 3, 0, Bbuf0, NOW, WV4);
        PHASE(Abuf1, 0, 1, Bbuf1,
              (ST_A(Abuf0, 0, t0 + 2), ST_A(Abuf0, 1, t0 + 2)), NOW);
        PHASE(Abuf1, 1, 0, Bbuf1,
              (ST_A(Abuf0, 2, t0 + 2), ST_A(Abuf0, 3, t0 + 2)), NOW);
        PHASE(Abuf1, 2, 0, Bbuf1,
              (ST_B(Bbuf1, 0, t0 + 3), ST_B(Bbuf1, 1, t0 + 3)), NOW);
        PHASE(Abuf1, 3, 0, Bbuf1,
              (ST_B(Bbuf1, 2, t0 + 3), ST_B(Bbuf1, 3, t0 + 3)), WV4);
    }
    // Tail iter: t0 = NT-2. Stage only A(NT-1); drain at phase 4.
    {
        PHASE(Abuf0, 0, 1, Bbuf0,
              (ST_A(Abuf1, 0, NT - 1), ST_A(Abuf1, 1, NT - 1),
               ST_A(Abuf1, 2, NT - 1), ST_A(Abuf1, 3, NT - 1)), NOW);
        PHASE(Abuf0, 1, 0, Bbuf0, NOW, NOW);
        PHASE(Abuf0, 2, 0, Bbuf0, NOW, NOW);
        PHASE(Abuf0, 3, 0, Bbuf0, NOW, WV0);
        PHASE(Abuf1, 0, 1, Bbuf1, NOW, NOW);
        PHASE(Abuf1, 1, 0, Bbuf1, NOW, NOW);
        PHASE(Abuf1, 2, 0, Bbuf1, NOW, NOW);
        PHASE(Abuf1, 3, 0, Bbuf1, NOW, NOW);
    }
#undef ST_A
#undef ST_B
#undef RD_B
#undef WV4
#undef WV0
#undef NOW
#undef PHASE

    // epilogue: D row = (l>>4)*4+reg, col = lane&15 within each 16x16 frag
    const int quad = kq4;
    if (MODE == 2) {
        __bf16* Qb = (__bf16*)Cout;
        const int part = bn >> 2;  // 0=Q 1=K 2=V  (256-col tiles, 4 per part)
#pragma unroll
        for (int mi = 0; mi < 8; ++mi) {
            const int srow0 = bm * 256 + wm * 128 + mi * 16 + quad * 4;
            const int b = srow0 >> 11;
            const int s0 = srow0 & 2047;
#pragma unroll
            for (int ni = 0; ni < 4; ++ni) {
                const int col = bn * 256 + wn * 64 + ni * 16 + r16;
                const float bb = HAS_BIAS ? bias[col] : 0.0f;
                const int c1 = col - part * 1024;
                if (part == 2) {
                    bf16x4 o;
#pragma unroll
                    for (int rr = 0; rr < 4; ++rr) o[rr] = (__bf16)(acc[mi][ni][rr] + bb);
                    *(bf16x4*)(Qb + 33554432 + (long long)b * 2097152 +
                               (long long)c1 * 2048 + s0) = o;
                } else {
                    __bf16* dst = Qb + (long long)part * 16777216 +
                                  (long long)b * 2097152 + (long long)s0 * 1024 + c1;
#pragma unroll
                    for (int rr = 0; rr < 4; ++rr) dst[rr * 1024] = (__bf16)(acc[mi][ni][rr] + bb);
                }
            }
        }
    } else {
        const long long cbase = (long long)z * sC;
#pragma unroll
        for (int mi = 0; mi < 8; ++mi) {
#pragma unroll
            for (int ni = 0; ni < 4; ++ni) {
                const int col = bn * 256 + wn * 64 + ni * 16 + r16;
                const float bb = HAS_BIAS ? bias[col] : 0.0f;
#pragma unroll
                for (int rr = 0; rr < 4; ++rr) {
                    const int row = bm * 256 + wm * 128 + mi * 16 + quad * 4 + rr;
                    const float v = acc[mi][ni][rr] * scale + bb;
                    if (MODE == 1)
                        ((float*)Cout)[cbase + (long long)row * ldc + col] = v;
                    else
                        ((__bf16*)Cout)[cbase + (long long)row * ldc + col] = (__bf16)v;
                }
            }
        }
    }
}

extern "C" void kernel_launch(void* const* d_in, const int* in_sizes, int n_in,
                              void* d_out, int out_size, void* d_ws, size_t ws_size,
                              hipStream_t stream) {
    const float* x  = (const float*)d_in[0];
    const float* wq = (const float*)d_in[1];
    const float* bq = (const float*)d_in[2];
    const float* wk = (const float*)d_in[3];
    const float* bk = (const float*)d_in[4];
    const float* wv = (const float*)d_in[5];
    const float* bv = (const float*)d_in[6];
    const float* wo = (const float*)d_in[7];
    const float* bo = (const float*)d_in[8];
    float* out = (float*)d_out;

    // ws layout (bf16 elems), ~200 MiB total.
    // Q, Kb, Vt must be contiguous in that order (MODE 2 epilogue).
    __bf16* ws  = (__bf16*)d_ws;
    __bf16* Xb  = ws;                   // 16,777,216 (phase 1; dead after QKV)
    __bf16* E   = ws;                   // 33,554,432 (phase 2, reuses Xb)
    __bf16* Q   = ws + 33554432;        // 16,777,216
    __bf16* Kb  = ws + 50331648;        // 16,777,216
    __bf16* Vt  = ws + 67108864;        // 16,777,216
    __bf16* Ctx = ws + 83886080;        // 16,777,216
    __bf16* WT  = ws + 100663296;       // 4,194,304
    float*  bc  = (float*)(ws + 104857600);  // 3072 fp32

    k_convert<<<8192, 256, 0, stream>>>(x, Xb);
    k_transpose_w<<<dim3(16, 16, 4), 256, 0, stream>>>(wq, wk, wv, wo, WT);
    k_bcat<<<12, 256, 0, stream>>>(bq, bk, bv, bc);

    // Fused QKV: [16384,3072] = Xb @ WT^T + bcat; writes Q, K, V^T
    // rowtiles=64, bnc=12 -> 768 blocks; gy=64 (z=0), rpx=8
    gemm_bt<2, true><<<768, 512, 0, stream>>>(
        Xb, WT, bc, Q, 1024, 1024, 1024, 0, 64, 8, 12, 1.0f, 0, 0, 0);

    // E[b] = Q[b] @ K[b]^T / 32   rowtiles=64 (8/z), bnc=8 -> 512 blocks
    gemm_bt<0, false><<<512, 512, 0, stream>>>(
        Q, Kb, nullptr, E, 1024, 1024, 1024, 2048, 8, 8, 8,
        0.03125f, 2097152, 2097152, 4194304);

    k_softmax<<<16384, 256, 0, stream>>>(E);

    // Ctx[b] = P[b] @ Vt[b]^T    rowtiles=64, bnc=4 -> 256 blocks
    gemm_bt<0, false><<<256, 512, 0, stream>>>(
        E, Vt, nullptr, Ctx, 2048, 2048, 2048, 1024, 8, 8, 4,
        1.0f, 4194304, 2097152, 2097152);

    // out = Ctx @ Wo^T + bo (fp32)  rowtiles=64, bnc=4 -> 256 blocks
    gemm_bt<1, true><<<256, 512, 0, stream>>>(
        Ctx, WT + 3145728, bo, out, 1024, 1024, 1024, 1024, 64, 8, 4,
        1.0f, 0, 0, 0);
}

// Round 4
// 446.758 us; speedup vs baseline: 1.5640x; 1.0221x over previous
//
#include <hip/hip_runtime.h>
#include <hip/hip_bf16.h>

// SpecAttn: out = softmax((x@Wq+bq)(x@Wk+bk)^T / 32) @ (x@Wv+bv) @ Wo + bo
// B=8, S=2048, H=1024. bf16 MFMA everywhere, fp32 accumulate.
// R9: R8 + (a) full 3-bit LDS swizzle: chunk' = (kh*4+kq4) ^ (row&7) ->
//     ds_read spreads over all 32 banks (R8's 2-bit XOR used banks 0-15
//     only -> 9.4M conflict cycles). kh offset becomes XOR-32 (two read
//     bases aro0/aro1). Staging still reads full permuted 128B rows
//     (coalesced). (b) MFMA operand swap (compute C^T frags): lane holds
//     4 consecutive OUTPUT COLUMNS -> bf16x4/f32x4 vector stores for
//     E/Ctx/out/Q/K epilogues (32 vector stores/thread vs 128 scalar).
//     V needs column-major out -> separate unswapped MODE-4 dispatch.
//     8-phase schedule, vmcnt(4)-at-ph4/ph8 ledger, setprio, barriers
//     identical to R8.

typedef __attribute__((ext_vector_type(8))) __bf16 bf16x8;
typedef __attribute__((ext_vector_type(4))) __bf16 bf16x4;
typedef __attribute__((ext_vector_type(4))) float  f32x4;
typedef __attribute__((ext_vector_type(8))) float  f32x8;

__device__ __forceinline__ void gl_lds16(const void* g, void* l) {
    __builtin_amdgcn_global_load_lds(
        (__attribute__((address_space(1))) const void*)g,
        (__attribute__((address_space(3))) void*)l, 16, 0, 0);
}

template <bool SWP>
__device__ __forceinline__ f32x4 mfma16(bf16x8 a, bf16x8 b, f32x4 c) {
    if constexpr (SWP)
        return __builtin_amdgcn_mfma_f32_16x16x32_bf16(b, a, c, 0, 0, 0);
    else
        return __builtin_amdgcn_mfma_f32_16x16x32_bf16(a, b, c, 0, 0, 0);
}

// ---------------- fp32 -> bf16 convert (x) ----------------
__global__ __launch_bounds__(256) void k_convert(const float* __restrict__ in,
                                                 __bf16* __restrict__ out) {
    const int i = blockIdx.x * 256 + threadIdx.x;   // 8 elems/thread, exact fit
    f32x8 a = *((const f32x8*)in + i);
    bf16x8 o;
#pragma unroll
    for (int j = 0; j < 8; ++j) o[j] = (__bf16)a[j];
    *((bf16x8*)out + i) = o;
}

// --- fp32 W[k][n] -> bf16 Wt[n][k] (1024x1024), z selects weight ---
__global__ __launch_bounds__(256) void k_transpose_w(
    const float* __restrict__ w0, const float* __restrict__ w1,
    const float* __restrict__ w2, const float* __restrict__ w3,
    __bf16* __restrict__ Wt) {
    const int z = blockIdx.z;
    const float* W = (z == 0) ? w0 : (z == 1) ? w1 : (z == 2) ? w2 : w3;
    __bf16* Wo = Wt + (long long)z * 1048576;
    __shared__ float t[64][65];
    const int tid = threadIdx.x;
    const int c4 = (tid & 15) * 4, r0 = tid >> 4;
    const int bx = blockIdx.x * 64, by = blockIdx.y * 64;
#pragma unroll
    for (int p = 0; p < 4; ++p) {
        const int r = r0 + p * 16;
        f32x4 v = *(const f32x4*)(W + (long long)(by + r) * 1024 + bx + c4);
#pragma unroll
        for (int j = 0; j < 4; ++j) t[r][c4 + j] = v[j];
    }
    __syncthreads();
#pragma unroll
    for (int p = 0; p < 4; ++p) {
        const int r = r0 + p * 16;
        bf16x4 o;
#pragma unroll
        for (int j = 0; j < 4; ++j) o[j] = (__bf16)t[c4 + j][r];
        *(bf16x4*)(Wo + (long long)(bx + r) * 1024 + by + c4) = o;
    }
}

// ------------- concat biases into bcat[3072] fp32 -------------
__global__ __launch_bounds__(256) void k_bcat(const float* __restrict__ bq,
                                              const float* __restrict__ bk,
                                              const float* __restrict__ bv,
                                              float* __restrict__ bc) {
    const int i = blockIdx.x * 256 + threadIdx.x;  // grid 12 -> 3072
    const float* s = (i < 1024) ? bq : (i < 2048 ? bk : bv);
    bc[i] = s[i & 1023];
}

// ------------- row softmax over 2048 cols, in place, bf16 -------------
__global__ __launch_bounds__(256) void k_softmax(__bf16* __restrict__ E) {
    __bf16* p = E + (long long)blockIdx.x * 2048;
    const int tid = threadIdx.x, l = tid & 63, w = tid >> 6;
    bf16x8 vb = *((const bf16x8*)p + tid);
    float v[8];
#pragma unroll
    for (int i = 0; i < 8; ++i) v[i] = (float)vb[i];
    float m = v[0];
#pragma unroll
    for (int i = 1; i < 8; ++i) m = fmaxf(m, v[i]);
    for (int off = 32; off > 0; off >>= 1) m = fmaxf(m, __shfl_xor(m, off));
    __shared__ float redm[4], reds[4];
    if (l == 0) redm[w] = m;
    __syncthreads();
    m = fmaxf(fmaxf(redm[0], redm[1]), fmaxf(redm[2], redm[3]));
    float e[8], s = 0.f;
#pragma unroll
    for (int i = 0; i < 8; ++i) { e[i] = __expf(v[i] - m); s += e[i]; }
    for (int off = 32; off > 0; off >>= 1) s += __shfl_xor(s, off);
    if (l == 0) reds[w] = s;
    __syncthreads();
    s = reds[0] + reds[1] + reds[2] + reds[3];
    const float inv = 1.0f / s;
    bf16x8 o;
#pragma unroll
    for (int i = 0; i < 8; ++i) o[i] = (__bf16)(e[i] * inv);
    *((bf16x8*)p + tid) = o;
}

// ------------- GEMM: C[z] = A[z] @ Bt[z]^T * scale (+bias) -------------
// 256x256 tile, BK=64, 8 waves (2x4), wave tile 128x64, 8-phase schedule.
// LDS [row 256][64], chunk swizzle c' = c ^ (row&7) (c in 0..7 of 16B).
// Staging: thread t -> LDS linear t*16 (+j*8192), global row t>>3 (+64j),
//          chunk (t&7)^((t>>3)&7): full permuted 128B rows, coalesced.
// MODE: 0 = bf16 C swapped, 1 = f32 C swapped, 2 = Q/K split swapped
//       (cols 0-1023 -> Q[b][s][h], 1024-2047 -> K[b][s][h]),
//       4 = V unswapped (cols -> Vt[b][h][s]).
// Swapped D-layout: row = r16 (m), cols = quad*4+rr (n) -> vector stores.
template <int MODE, bool HAS_BIAS>
__global__ __launch_bounds__(512, 2) void gemm_bt(
    const __bf16* __restrict__ A, const __bf16* __restrict__ Bt,
    const float* __restrict__ bias, void* __restrict__ Cout,
    int K, int lda, int ldb, int ldc, int gy, int rpx, int bnc,
    float scale, long long sA, long long sB, long long sC) {
    constexpr bool SWP = (MODE != 4);
    __shared__ __align__(16) __bf16 Abuf0[16384];
    __shared__ __align__(16) __bf16 Bbuf0[16384];
    __shared__ __align__(16) __bf16 Abuf1[16384];
    __shared__ __align__(16) __bf16 Bbuf1[16384];

    // swizzled block mapping
    const int lid = blockIdx.x;
    const int xcd = lid & 7;
    const int jj = lid >> 3;
    const int bn = jj % bnc;
    const int rt = xcd * rpx + jj / bnc;
    const int z = rt / gy;
    const int bm = rt - z * gy;

    const __bf16* Ab = A + (long long)z * sA;
    const __bf16* Bb = Bt + (long long)z * sB;

    const int tid = threadIdx.x;
    const int l = tid & 63, w = tid >> 6;   // lane, wave 0..7
    const int wm = w >> 2, wn = w & 3;      // 2 x 4 wave grid

    // staging: thread t covers rows (t>>3)+64j, global chunk (t&7)^((t>>3)&7)
    const int rA = tid >> 3;
    const int cswz = (tid & 7) ^ (rA & 7);
    const __bf16* aSg = Ab + (long long)(bm * 256 + rA) * lda + cswz * 8;
    const __bf16* bSg = Bb + (long long)(bn * 256 + rA) * ldb + cswz * 8;
    const long long a64 = (long long)lda * 64;
    const long long b64 = (long long)ldb * 64;
    const int ldst = tid * 16;              // LDS byte base (linear)

    // ds-read fragment offsets (elements): row stride 64.
    // chunk for (kq4,kh): (kh*4+kq4) ^ (r16&7); kh=1 base = kh=0 base ^ 32.
    const int r16 = l & 15, kq4 = l >> 4;
    const int sw0 = kq4 ^ (r16 & 7);
    const int aro0 = (wm * 128 + r16) * 64 + sw0 * 8;
    const int aro1 = aro0 ^ 32;
    const int bro0 = (wn * 64 + r16) * 64 + sw0 * 8;
    const int bro1 = bro0 ^ 32;

    f32x4 acc[8][4] = {};
    bf16x8 bf[4][2];

#define ST_A(buf, j, t)                                                    \
    gl_lds16(aSg + (j) * a64 + (long long)(t) * 64,                        \
             (char*)(buf) + ldst + (j) * 8192)
#define ST_B(buf, j, t)                                                    \
    gl_lds16(bSg + (j) * b64 + (long long)(t) * 64,                        \
             (char*)(buf) + ldst + (j) * 8192)

#define RD_B(buf)                                                          \
    do {                                                                   \
        _Pragma("unroll") for (int ni = 0; ni < 4; ++ni) {                 \
            bf[ni][0] = *(const bf16x8*)((buf) + bro0 + ni * 1024);        \
            bf[ni][1] = *(const bf16x8*)((buf) + bro1 + ni * 1024);        \
        }                                                                  \
    } while (0)

#define WV4 asm volatile("s_waitcnt vmcnt(4)" ::: "memory")
#define WV0 asm volatile("s_waitcnt vmcnt(0)" ::: "memory")
#define NOW ((void)0)

// One phase: ds-read A mi-pair (and B on p==0) || stage -> barrier ->
// lgkmcnt(0) -> setprio(1)+16 MFMA -> [vmcnt] -> barrier.
#define PHASE(Abuf, p, RB, RBUF, STAGES, WAIT)                                 \
    do {                                                                      \
        bf16x8 af0k0 = *(const bf16x8*)((Abuf) + aro0 + (2 * (p)) * 1024);     \
        bf16x8 af0k1 = *(const bf16x8*)((Abuf) + aro1 + (2 * (p)) * 1024);     \
        bf16x8 af1k0 = *(const bf16x8*)((Abuf) + aro0 + (2 * (p) + 1) * 1024); \
        bf16x8 af1k1 = *(const bf16x8*)((Abuf) + aro1 + (2 * (p) + 1) * 1024); \
        if (RB) RD_B(RBUF);                                                   \
        STAGES;                                                               \
        __builtin_amdgcn_s_barrier();                                         \
        asm volatile("s_waitcnt lgkmcnt(0)" ::: "memory");                    \
        __builtin_amdgcn_sched_barrier(0);                                    \
        __builtin_amdgcn_s_setprio(1);                                        \
        _Pragma("unroll") for (int ni = 0; ni < 4; ++ni) {                    \
            acc[2 * (p)][ni] = mfma16<SWP>(af0k0, bf[ni][0], acc[2*(p)][ni]); \
            acc[2 * (p)][ni] = mfma16<SWP>(af0k1, bf[ni][1], acc[2*(p)][ni]); \
            acc[2*(p)+1][ni] = mfma16<SWP>(af1k0, bf[ni][0], acc[2*(p)+1][ni]);\
            acc[2*(p)+1][ni] = mfma16<SWP>(af1k1, bf[ni][1], acc[2*(p)+1][ni]);\
        }                                                                     \
        __builtin_amdgcn_s_setprio(0);                                        \
        WAIT;                                                                 \
        __builtin_amdgcn_sched_barrier(0);                                    \
        __builtin_amdgcn_s_barrier();                                         \
    } while (0)

    // Prologue: stage B(0), A(0), B(1); force B(0),A(0) (keep B(1) in flight).
    ST_B(Bbuf0, 0, 0); ST_B(Bbuf0, 1, 0); ST_B(Bbuf0, 2, 0); ST_B(Bbuf0, 3, 0);
    ST_A(Abuf0, 0, 0); ST_A(Abuf0, 1, 0); ST_A(Abuf0, 2, 0); ST_A(Abuf0, 3, 0);
    ST_B(Bbuf1, 0, 1); ST_B(Bbuf1, 1, 1); ST_B(Bbuf1, 2, 1); ST_B(Bbuf1, 3, 1);
    WV4;
    __builtin_amdgcn_s_barrier();

    const int NT = K >> 6;  // K-tiles of 64; NT even, >= 4 for all dispatches
    // Main iters: compute tiles (t0, t0+1); stage A(t0+1), B/A(t0+2), B(t0+3).
    for (int t0 = 0; t0 + 3 < NT; t0 += 2) {
        PHASE(Abuf0, 0, 1, Bbuf0,
              (ST_A(Abuf1, 0, t0 + 1), ST_A(Abuf1, 1, t0 + 1),
               ST_A(Abuf1, 2, t0 + 1), ST_A(Abuf1, 3, t0 + 1)), NOW);
        PHASE(Abuf0, 1, 0, Bbuf0,
              (ST_B(Bbuf0, 0, t0 + 2), ST_B(Bbuf0, 1, t0 + 2)), NOW);
        PHASE(Abuf0, 2, 0, Bbuf0,
              (ST_B(Bbuf0, 2, t0 + 2), ST_B(Bbuf0, 3, t0 + 2)), NOW);
        PHASE(Abuf0, 3, 0, Bbuf0, NOW, WV4);
        PHASE(Abuf1, 0, 1, Bbuf1,
              (ST_A(Abuf0, 0, t0 + 2), ST_A(Abuf0, 1, t0 + 2)), NOW);
        PHASE(Abuf1, 1, 0, Bbuf1,
              (ST_A(Abuf0, 2, t0 + 2), ST_A(Abuf0, 3, t0 + 2)), NOW);
        PHASE(Abuf1, 2, 0, Bbuf1,
              (ST_B(Bbuf1, 0, t0 + 3), ST_B(Bbuf1, 1, t0 + 3)), NOW);
        PHASE(Abuf1, 3, 0, Bbuf1,
              (ST_B(Bbuf1, 2, t0 + 3), ST_B(Bbuf1, 3, t0 + 3)), WV4);
    }
    // Tail iter: t0 = NT-2. Stage only A(NT-1); drain at phase 4.
    {
        PHASE(Abuf0, 0, 1, Bbuf0,
              (ST_A(Abuf1, 0, NT - 1), ST_A(Abuf1, 1, NT - 1),
               ST_A(Abuf1, 2, NT - 1), ST_A(Abuf1, 3, NT - 1)), NOW);
        PHASE(Abuf0, 1, 0, Bbuf0, NOW, NOW);
        PHASE(Abuf0, 2, 0, Bbuf0, NOW, NOW);
        PHASE(Abuf0, 3, 0, Bbuf0, NOW, WV0);
        PHASE(Abuf1, 0, 1, Bbuf1, NOW, NOW);
        PHASE(Abuf1, 1, 0, Bbuf1, NOW, NOW);
        PHASE(Abuf1, 2, 0, Bbuf1, NOW, NOW);
        PHASE(Abuf1, 3, 0, Bbuf1, NOW, NOW);
    }
#undef ST_A
#undef ST_B
#undef RD_B
#undef WV4
#undef WV0
#undef NOW
#undef PHASE

    const int quad = kq4;
    if constexpr (MODE == 2) {
        // swapped: row(s) = ...+r16, cols = ...+quad*4+rr -> bf16x4 stores
        __bf16* Qb = (__bf16*)Cout;
        const int part = bn >> 2;  // 0=Q 1=K
#pragma unroll
        for (int mi = 0; mi < 8; ++mi) {
            const int srow0 = bm * 256 + wm * 128 + mi * 16 + r16;
            const int b = srow0 >> 11;
            const int s0 = srow0 & 2047;
#pragma unroll
            for (int ni = 0; ni < 4; ++ni) {
                const int col0 = bn * 256 + wn * 64 + ni * 16 + quad * 4;
                const f32x4 bb = *(const f32x4*)(bias + col0);
                const int c1 = col0 - part * 1024;
                bf16x4 o;
#pragma unroll
                for (int rr = 0; rr < 4; ++rr) o[rr] = (__bf16)(acc[mi][ni][rr] + bb[rr]);
                *(bf16x4*)(Qb + (long long)part * 16777216 +
                           (long long)b * 2097152 + (long long)s0 * 1024 + c1) = o;
            }
        }
    } else if constexpr (MODE == 4) {
        // unswapped: col(h) = ...+r16, rows(s) = ...+quad*4+rr -> bf16x4 along s
        __bf16* Vb = (__bf16*)Cout;
#pragma unroll
        for (int mi = 0; mi < 8; ++mi) {
            const int srow0 = bm * 256 + wm * 128 + mi * 16 + quad * 4;
            const int b = srow0 >> 11;
            const int s0 = srow0 & 2047;
#pragma unroll
            for (int ni = 0; ni < 4; ++ni) {
                const int c1 = bn * 256 + wn * 64 + ni * 16 + r16;
                const float bb = HAS_BIAS ? bias[c1] : 0.0f;
                bf16x4 o;
#pragma unroll
                for (int rr = 0; rr < 4; ++rr) o[rr] = (__bf16)(acc[mi][ni][rr] + bb);
                *(bf16x4*)(Vb + (long long)b * 2097152 +
                           (long long)c1 * 2048 + s0) = o;
            }
        }
    } else {
        // MODE 0/1 swapped row-major: vector store of 4 consecutive cols
        const long long cbase = (long long)z * sC;
#pragma unroll
        for (int mi = 0; mi < 8; ++mi) {
            const int row = bm * 256 + wm * 128 + mi * 16 + r16;
#pragma unroll
            for (int ni = 0; ni < 4; ++ni) {
                const int col0 = bn * 256 + wn * 64 + ni * 16 + quad * 4;
                f32x4 v;
                if constexpr (HAS_BIAS) {
                    const f32x4 bb = *(const f32x4*)(bias + col0);
#pragma unroll
                    for (int rr = 0; rr < 4; ++rr) v[rr] = acc[mi][ni][rr] * scale + bb[rr];
                } else {
#pragma unroll
                    for (int rr = 0; rr < 4; ++rr) v[rr] = acc[mi][ni][rr] * scale;
                }
                if constexpr (MODE == 1) {
                    *(f32x4*)((float*)Cout + cbase + (long long)row * ldc + col0) = v;
                } else {
                    bf16x4 o;
#pragma unroll
                    for (int rr = 0; rr < 4; ++rr) o[rr] = (__bf16)v[rr];
                    *(bf16x4*)((__bf16*)Cout + cbase + (long long)row * ldc + col0) = o;
                }
            }
        }
    }
}

extern "C" void kernel_launch(void* const* d_in, const int* in_sizes, int n_in,
                              void* d_out, int out_size, void* d_ws, size_t ws_size,
                              hipStream_t stream) {
    const float* x  = (const float*)d_in[0];
    const float* wq = (const float*)d_in[1];
    const float* bq = (const float*)d_in[2];
    const float* wk = (const float*)d_in[3];
    const float* bk = (const float*)d_in[4];
    const float* wv = (const float*)d_in[5];
    const float* bv = (const float*)d_in[6];
    const float* wo = (const float*)d_in[7];
    const float* bo = (const float*)d_in[8];
    float* out = (float*)d_out;

    // ws layout (bf16 elems), ~200 MiB total.
    // Q, Kb, Vt must be contiguous in that order (MODE 2 epilogue).
    __bf16* ws  = (__bf16*)d_ws;
    __bf16* Xb  = ws;                   // 16,777,216 (phase 1; dead after QKV)
    __bf16* E   = ws;                   // 33,554,432 (phase 2, reuses Xb)
    __bf16* Q   = ws + 33554432;        // 16,777,216
    __bf16* Kb  = ws + 50331648;        // 16,777,216
    __bf16* Vt  = ws + 67108864;        // 16,777,216
    __bf16* Ctx = ws + 83886080;        // 16,777,216
    __bf16* WT  = ws + 100663296;       // 4,194,304
    float*  bc  = (float*)(ws + 104857600);  // 3072 fp32

    k_convert<<<8192, 256, 0, stream>>>(x, Xb);
    k_transpose_w<<<dim3(16, 16, 4), 256, 0, stream>>>(wq, wk, wv, wo, WT);
    k_bcat<<<12, 256, 0, stream>>>(bq, bk, bv, bc);

    // Q,K: [16384,2048] = Xb @ WT[0:2048]^T + bcat -> Q, K (split epilogue)
    // rowtiles=64, bnc=8 -> 512 blocks; rpx=8
    gemm_bt<2, true><<<512, 512, 0, stream>>>(
        Xb, WT, bc, Q, 1024, 1024, 1024, 0, 64, 8, 8, 1.0f, 0, 0, 0);

    // V: [16384,1024] = Xb @ WT[2048:3072]^T + bcat[2048:] -> Vt[b][h][s]
    // rowtiles=64, bnc=4 -> 256 blocks; rpx=8
    gemm_bt<4, true><<<256, 512, 0, stream>>>(
        Xb, WT + 2097152, bc + 2048, Vt, 1024, 1024, 1024, 0, 64, 8, 4,
        1.0f, 0, 0, 0);

    // E[b] = Q[b] @ K[b]^T / 32   rowtiles=64 (8/z), bnc=8 -> 512 blocks
    gemm_bt<0, false><<<512, 512, 0, stream>>>(
        Q, Kb, nullptr, E, 1024, 1024, 1024, 2048, 8, 8, 8,
        0.03125f, 2097152, 2097152, 4194304);

    k_softmax<<<16384, 256, 0, stream>>>(E);

    // Ctx[b] = P[b] @ Vt[b]^T    rowtiles=64, bnc=4 -> 256 blocks
    gemm_bt<0, false><<<256, 512, 0, stream>>>(
        E, Vt, nullptr, Ctx, 2048, 2048, 2048, 1024, 8, 8, 4,
        1.0f, 4194304, 2097152, 2097152);

    // out = Ctx @ Wo^T + bo (fp32)  rowtiles=64, bnc=4 -> 256 blocks
    gemm_bt<1, true><<<256, 512, 0, stream>>>(
        Ctx, WT + 3145728, bo, out, 1024, 1024, 1024, 1024, 64, 8, 4,
        1.0f, 0, 0, 0);
}